// Round 2
// baseline (828.677 us; speedup 1.0000x reference)
//
#include <hip/hip_runtime.h>
#include <hip/hip_bf16.h>

#define HW    3136
#define CIN   64
#define MIDC  32
#define HEADS 8
#define DTOT  256
#define COUTC 64
#define WDIM  56

// ---------------- Kernel 1: fused QKV 1x1 conv (fp32 in -> fp32 ws) ----------
__global__ __launch_bounds__(256) void qkv_kernel(
    const float* __restrict__ x,
    const float* __restrict__ Wq, const float* __restrict__ bq,
    const float* __restrict__ Wk, const float* __restrict__ bk,
    const float* __restrict__ Wv, const float* __restrict__ bv,
    float* __restrict__ qb, float* __restrict__ kb, float* __restrict__ vb)
{
    int p = blockIdx.x * 256 + threadIdx.x;
    int d = blockIdx.y;               // d = mid*8 + head  (channel of 256)
    if (p >= HW) return;
    float aq = bq[d], ak = bk[d], av = bv[d];
    #pragma unroll 8
    for (int c = 0; c < CIN; ++c) {
        float xv = x[c * HW + p];           // coalesced across p
        aq += Wq[d * CIN + c] * xv;         // uniform (scalar) weight reads
        ak += Wk[d * CIN + c] * xv;
        av += Wv[d * CIN + c] * xv;
    }
    qb[d * HW + p] = aq;
    kb[d * HW + p] = ak;
    vb[d * HW + p] = av;
}

// ---------------- Kernel 2: attention, one wave per (head, query) ------------
// layout: qb/kb/vb[(m*8+h)*HW + pos], fp32
__global__ __launch_bounds__(256) void attn_kernel(
    const float* __restrict__ qb, const float* __restrict__ kb,
    const float* __restrict__ vb,
    const float* __restrict__ rowt, const float* __restrict__ colt,
    float* __restrict__ ob)
{
    __shared__ float RC[4][112];      // per wave: [0..55]=inv*R[k], [56..111]=inv*C[l]
    const int tid  = threadIdx.x;
    const int wave = tid >> 6, lane = tid & 63;
    const int G = blockIdx.x * 4 + wave;     // 0 .. 25087
    const int h = G / HW, p = G % HW;
    const int qi = p / WDIM, qj = p % WDIM;
    const float inv = 0.125f;                 // 1/sqrt(64)

    // every lane holds the full 32-dim query (wave-uniform broadcast loads)
    float qv[MIDC];
    #pragma unroll
    for (int m = 0; m < MIDC; ++m) qv[m] = qb[(m * HEADS + h) * HW + p];

    // relative-position terms:
    //   R[k] = inv * sum_{c<16} q[c]    * row_table[k - qi + 55][c]
    //   C[l] = inv * sum_{c<16} q[16+c] * col_table[l - qj + 55][c]
    if (lane < WDIM) {
        int rr = lane - qi + (WDIM - 1);
        float s = 0.f;
        #pragma unroll
        for (int c = 0; c < 16; ++c) s += qv[c] * rowt[rr * 16 + c];
        RC[wave][lane] = s * inv;
        int cc = lane - qj + (WDIM - 1);
        float s2 = 0.f;
        #pragma unroll
        for (int c = 0; c < 16; ++c) s2 += qv[16 + c] * colt[cc * 16 + c];
        RC[wave][WDIM + lane] = s2 * inv;
    }
    __syncthreads();

    // per-lane online softmax over keys kk = lane, lane+64, ... (exactly 49 iters)
    float mrun = -1e30f, lsum = 0.f;
    float acc[MIDC];
    #pragma unroll
    for (int m = 0; m < MIDC; ++m) acc[m] = 0.f;

    int kr = lane / WDIM, kl = lane % WDIM;   // key (row, col), advanced by +64/iter
    for (int kk = lane; kk < HW; kk += 64) {
        float s = 0.f;
        #pragma unroll
        for (int m = 0; m < MIDC; ++m)
            s += qv[m] * kb[(m * HEADS + h) * HW + kk];   // coalesced across lanes
        float score = inv * s + RC[wave][kr] + RC[wave][WDIM + kl];
        if (score > mrun) {               // rare rescale (amortized ~ln(49) times)
            float corr = __expf(mrun - score);
            lsum *= corr;
            #pragma unroll
            for (int m = 0; m < MIDC; ++m) acc[m] *= corr;
            mrun = score;
        }
        float e = __expf(score - mrun);
        lsum += e;
        #pragma unroll
        for (int m = 0; m < MIDC; ++m)
            acc[m] += e * vb[(m * HEADS + h) * HW + kk];
        kl += 8; kr += 1;                 // advance position by 64 = 56 + 8
        if (kl >= WDIM) { kl -= WDIM; ++kr; }
    }

    // merge 64 per-lane online-softmax states (xor butterfly; all lanes converge)
    for (int off = 32; off > 0; off >>= 1) {
        float m2 = __shfl_xor(mrun, off, 64);
        float l2 = __shfl_xor(lsum, off, 64);
        float nm = fmaxf(mrun, m2);
        float ea = __expf(mrun - nm), eb = __expf(m2 - nm);
        lsum = lsum * ea + l2 * eb;
        #pragma unroll
        for (int m = 0; m < MIDC; ++m)
            acc[m] = acc[m] * ea + __shfl_xor(acc[m], off, 64) * eb;
        mrun = nm;
    }

    if (lane == 0) {
        float invl = 1.f / lsum;
        #pragma unroll
        for (int m = 0; m < MIDC; ++m)
            ob[(m * HEADS + h) * HW + p] = acc[m] * invl;
    }
}

// ---------------- Kernel 3: output 1x1 conv (fp32 ws -> fp32 out) ------------
__global__ __launch_bounds__(256) void outproj_kernel(
    const float* __restrict__ ob, const float* __restrict__ Wo,
    const float* __restrict__ bo, float* __restrict__ out)
{
    int p = blockIdx.x * 256 + threadIdx.x;
    int d = blockIdx.y;
    if (p >= HW) return;
    float s = bo[d];
    #pragma unroll 8
    for (int c = 0; c < DTOT; ++c)
        s += Wo[d * DTOT + c] * ob[c * HW + p];
    out[d * HW + p] = s;
}

extern "C" void kernel_launch(void* const* d_in, const int* in_sizes, int n_in,
                              void* d_out, int out_size, void* d_ws, size_t ws_size,
                              hipStream_t stream)
{
    const float* x    = (const float*)d_in[0];
    const float* Wq   = (const float*)d_in[1];
    const float* bq   = (const float*)d_in[2];
    const float* Wk   = (const float*)d_in[3];
    const float* bk   = (const float*)d_in[4];
    const float* Wv   = (const float*)d_in[5];
    const float* bv   = (const float*)d_in[6];
    const float* Wo   = (const float*)d_in[7];
    const float* bo   = (const float*)d_in[8];
    const float* rowt = (const float*)d_in[9];
    const float* colt = (const float*)d_in[10];
    float* out = (float*)d_out;

    float* qb = (float*)d_ws;              // 256*3136 fp32
    float* kb = qb + DTOT * HW;
    float* vb = kb + DTOT * HW;
    float* ob = vb + DTOT * HW;            // total 12.9 MB ws

    qkv_kernel<<<dim3(13, DTOT), 256, 0, stream>>>(x, Wq, bq, Wk, bk, Wv, bv, qb, kb, vb);
    attn_kernel<<<dim3(HEADS * HW / 4), 256, 0, stream>>>(qb, kb, vb, rowt, colt, ob);
    outproj_kernel<<<dim3(13, COUTC), 256, 0, stream>>>(ob, Wo, bo, out);
}

// Round 3
// 199.441 us; speedup vs baseline: 4.1550x; 4.1550x over previous
//
#include <hip/hip_runtime.h>
#include <hip/hip_bf16.h>

#define HW    3136
#define CIN   64
#define MIDC  32
#define HEADS 8
#define DTOT  256
#define COUTC 64
#define WDIM  56
#define QT    16          // queries per block (one wave)
#define NKT   49          // key tiles of 64 (49*64 = 3136 exactly, no masking)

typedef unsigned short ushort_t;
typedef unsigned int   uint_t;
typedef __attribute__((ext_vector_type(8))) short short8;   // 8 bf16 = 4 VGPRs
typedef __attribute__((ext_vector_type(4))) float f32x4;

__device__ __forceinline__ float bf2f(ushort_t u) {
    return __uint_as_float(((uint_t)u) << 16);
}
__device__ __forceinline__ ushort_t f2bf(float f) {          // RNE
    uint_t u = __float_as_uint(f);
    u += 0x7fff + ((u >> 16) & 1);
    return (ushort_t)(u >> 16);
}

// ---------------- Kernel 1: QKV 1x1 conv, fp32 in -> bf16 ws -----------------
// qb,kb: [h][pos][32]  (row-major per position, 64B rows)
// vb:    [h][ch][pos]  (transposed)
__global__ __launch_bounds__(256) void qkv_kernel(
    const float* __restrict__ x,
    const float* __restrict__ Wq, const float* __restrict__ bq,
    const float* __restrict__ Wk, const float* __restrict__ bk,
    const float* __restrict__ Wv, const float* __restrict__ bv,
    ushort_t* __restrict__ qb, ushort_t* __restrict__ kb, ushort_t* __restrict__ vb)
{
    int p  = blockIdx.x * 256 + threadIdx.x;
    int h  = blockIdx.y;
    int m0 = blockIdx.z * 8;           // this block covers mids m0..m0+7
    if (p >= HW) return;
    float qa[8], ka[8], va[8];
    #pragma unroll
    for (int mm = 0; mm < 8; ++mm) {
        int d = (m0 + mm) * HEADS + h;
        qa[mm] = bq[d]; ka[mm] = bk[d]; va[mm] = bv[d];
    }
    #pragma unroll 4
    for (int c = 0; c < CIN; ++c) {
        float xv = x[c * HW + p];      // coalesced across lanes
        #pragma unroll
        for (int mm = 0; mm < 8; ++mm) {
            int d = (m0 + mm) * HEADS + h;   // uniform weight reads
            qa[mm] += Wq[d * CIN + c] * xv;
            ka[mm] += Wk[d * CIN + c] * xv;
            va[mm] += Wv[d * CIN + c] * xv;
        }
    }
    // Q,K: pack 8 bf16 -> 16B store at [h][p][m0]
    uint_t qw[4], kw[4];
    #pragma unroll
    for (int i = 0; i < 4; ++i) {
        qw[i] = (uint_t)f2bf(qa[2*i]) | ((uint_t)f2bf(qa[2*i+1]) << 16);
        kw[i] = (uint_t)f2bf(ka[2*i]) | ((uint_t)f2bf(ka[2*i+1]) << 16);
    }
    *(uint4*)&qb[(size_t)h * HW * MIDC + p * MIDC + m0] = *(uint4*)qw;
    *(uint4*)&kb[(size_t)h * HW * MIDC + p * MIDC + m0] = *(uint4*)kw;
    // V transposed: [h][m][p], coalesced 2B stores per channel
    #pragma unroll
    for (int mm = 0; mm < 8; ++mm)
        vb[(size_t)h * HW * MIDC + (m0 + mm) * HW + p] = f2bf(va[mm]);
}

// ---------------- Kernel 2: MFMA flash attention -----------------------------
// grid (196, 8): 196 q-tiles of 16 x 8 heads. 64 threads = 1 wave.
__global__ __launch_bounds__(64) void attn_kernel(
    const ushort_t* __restrict__ qb, const ushort_t* __restrict__ kb,
    const ushort_t* __restrict__ vb,
    const float* __restrict__ rowt, const float* __restrict__ colt,
    float* __restrict__ ob)
{
    __shared__ ushort_t Qs[QT][MIDC];        // 1 KB
    __shared__ float    Rb[QT][57];          // 3648 B (57: break bank conflicts)
    __shared__ float    Cb[QT][57];
    __shared__ ushort_t Pl[QT][72];          // P tile [q][key], pad 72, 2304 B

    const int lane  = threadIdx.x;
    const int h     = blockIdx.y;
    const int qbase = blockIdx.x * QT;
    const float inv = 0.125f;                 // 1/sqrt(64)

    const ushort_t* Qh = qb + (size_t)h * HW * MIDC;
    const ushort_t* Kh = kb + (size_t)h * HW * MIDC;
    const ushort_t* Vh = vb + (size_t)h * HW * MIDC;   // [ch][pos]

    // ---- stage Q tile (16 q x 32 ch) into LDS: 64 threads x 8 elems (16B)
    {
        int r = lane >> 2, c = (lane & 3) * 8;
        *(uint4*)&Qs[r][c] = *(const uint4*)&Qh[(size_t)(qbase + r) * MIDC + c];
    }
    __syncthreads();

    // ---- per-block rel-pos bias tables (fp32):
    //  Rb[qL][ki] = inv * sum_{c<16}  Q[qL][c]    * rowt[ki - qi + 55][c]
    //  Cb[qL][kj] = inv * sum_{c<16}  Q[qL][16+c] * colt[kj - qj + 55][c]
    for (int idx = lane; idx < QT * WDIM; idx += 64) {   // 896 = 64*14 exact
        int qL = idx / WDIM, kp = idx % WDIM;
        int qg = qbase + qL, qi = qg / WDIM, qj = qg % WDIM;
        const float* rt = &rowt[(kp - qi + WDIM - 1) * 16];
        const float* ct = &colt[(kp - qj + WDIM - 1) * 16];
        float s = 0.f, s2 = 0.f;
        #pragma unroll
        for (int c = 0; c < 16; ++c) {
            s  += bf2f(Qs[qL][c])      * rt[c];
            s2 += bf2f(Qs[qL][16 + c]) * ct[c];
        }
        Rb[qL][kp] = s * inv;
        Cb[qL][kp] = s2 * inv;
    }
    __syncthreads();

    const int qL  = lane & 15;          // this lane's query (col index everywhere)
    const int grp = lane >> 4;          // lane quad-group 0..3
    // Q B-fragment (constant over k-loop): B[k=ch][n=q], 8 contiguous ch
    short8 qfrag = *(const short8*)&Qs[qL][grp * 8];

    float m_run = -1e30f, l_run = 0.f;
    f32x4 o0 = {0.f, 0.f, 0.f, 0.f};    // O^T acc, ch rows  0..15
    f32x4 o1 = {0.f, 0.f, 0.f, 0.f};    // O^T acc, ch rows 16..31

    for (int kt = 0; kt < NKT; ++kt) {
        const int kb0 = kt * 64;
        // ---- K A-frags (4 subtiles of 16 keys) + V^T A-frags (issue early)
        short8 kf[4];
        #pragma unroll
        for (int s = 0; s < 4; ++s)
            kf[s] = *(const short8*)&Kh[(size_t)(kb0 + s * 16 + qL) * MIDC + grp * 8];
        short8 vf[2][2];   // [chhalf][khalf]
        #pragma unroll
        for (int ch = 0; ch < 2; ++ch)
            #pragma unroll
            for (int kh = 0; kh < 2; ++kh)
                vf[ch][kh] = *(const short8*)
                    &Vh[(size_t)(ch * 16 + qL) * HW + kb0 + kh * 32 + grp * 8];

        // ---- S^T = K . Q^T  (D rows = keys, cols = queries)
        f32x4 sc[4];
        #pragma unroll
        for (int s = 0; s < 4; ++s) {
            f32x4 z = {0.f, 0.f, 0.f, 0.f};
            sc[s] = __builtin_amdgcn_mfma_f32_16x16x32_bf16(kf[s], qfrag, z, 0, 0, 0);
        }

        // ---- bias + online softmax (lane owns 16 scores, all for query qL)
        float sv[16];
        float smax = -1e30f;
        #pragma unroll
        for (int s = 0; s < 4; ++s)
            #pragma unroll
            for (int r = 0; r < 4; ++r) {
                int klocal = s * 16 + grp * 4 + r;
                int key = kb0 + klocal;
                int ki = key / WDIM, kj = key % WDIM;
                float v = sc[s][r] * inv + Rb[qL][ki] + Cb[qL][kj];
                sv[s * 4 + r] = v;
                smax = fmaxf(smax, v);
            }
        smax = fmaxf(smax, __shfl_xor(smax, 16));
        smax = fmaxf(smax, __shfl_xor(smax, 32));
        float m_new = fmaxf(m_run, smax);
        float alpha = __expf(m_run - m_new);
        float lsum = 0.f;
        ushort_t pb[16];
        #pragma unroll
        for (int j = 0; j < 16; ++j) {
            float p = __expf(sv[j] - m_new);
            lsum += p;
            pb[j] = f2bf(p);
        }
        lsum += __shfl_xor(lsum, 16);
        lsum += __shfl_xor(lsum, 32);
        l_run = l_run * alpha + lsum;
        m_run = m_new;
        #pragma unroll
        for (int i = 0; i < 4; ++i) { o0[i] *= alpha; o1[i] *= alpha; }

        // ---- P -> LDS (bf16), [q][key] with pad; same-wave DS ops are in-order
        #pragma unroll
        for (int s = 0; s < 4; ++s) {
            uint2 w;
            w.x = (uint_t)pb[s*4+0] | ((uint_t)pb[s*4+1] << 16);
            w.y = (uint_t)pb[s*4+2] | ((uint_t)pb[s*4+3] << 16);
            *(uint2*)&Pl[qL][s * 16 + grp * 4] = w;
        }

        // ---- O^T += V^T . P^T   (4 MFMAs: 2 ch-halves x 2 key-halves)
        #pragma unroll
        for (int kh = 0; kh < 2; ++kh) {
            short8 pf = *(const short8*)&Pl[qL][kh * 32 + grp * 8];
            o0 = __builtin_amdgcn_mfma_f32_16x16x32_bf16(vf[0][kh], pf, o0, 0, 0, 0);
            o1 = __builtin_amdgcn_mfma_f32_16x16x32_bf16(vf[1][kh], pf, o1, 0, 0, 0);
        }
    }

    // ---- epilogue: O / l, write ob fp32 [h*32+ch][pos]
    float invl = 1.f / l_run;
    int qg = qbase + qL;
    #pragma unroll
    for (int r = 0; r < 4; ++r) {
        int ch0 = grp * 4 + r;
        ob[(size_t)(h * MIDC + ch0) * HW + qg]        = o0[r] * invl;
        ob[(size_t)(h * MIDC + ch0 + 16) * HW + qg]   = o1[r] * invl;
    }
}

// ---------------- Kernel 3: output 1x1 conv (fp32 ws -> fp32 out) ------------
// ob channel layout: c_total = m*8+h lives at row (h*32+m)
__global__ __launch_bounds__(256) void outproj_kernel(
    const float* __restrict__ ob, const float* __restrict__ Wo,
    const float* __restrict__ bo, float* __restrict__ out)
{
    int p = blockIdx.x * 256 + threadIdx.x;
    int d = blockIdx.y;
    if (p >= HW) return;
    float s = bo[d];
    #pragma unroll 8
    for (int c = 0; c < DTOT; ++c) {
        int m = c >> 3, h = c & 7;
        s += Wo[d * DTOT + c] * ob[(size_t)(h * MIDC + m) * HW + p];
    }
    out[d * HW + p] = s;
}

extern "C" void kernel_launch(void* const* d_in, const int* in_sizes, int n_in,
                              void* d_out, int out_size, void* d_ws, size_t ws_size,
                              hipStream_t stream)
{
    const float* x    = (const float*)d_in[0];
    const float* Wq   = (const float*)d_in[1];
    const float* bq   = (const float*)d_in[2];
    const float* Wk   = (const float*)d_in[3];
    const float* bk   = (const float*)d_in[4];
    const float* Wv   = (const float*)d_in[5];
    const float* bv   = (const float*)d_in[6];
    const float* Wo   = (const float*)d_in[7];
    const float* bo   = (const float*)d_in[8];
    const float* rowt = (const float*)d_in[9];
    const float* colt = (const float*)d_in[10];
    float* out = (float*)d_out;

    const size_t nkv = (size_t)HEADS * HW * MIDC;       // 802816 elems
    ushort_t* qbw = (ushort_t*)d_ws;
    ushort_t* kbw = qbw + nkv;
    ushort_t* vbw = kbw + nkv;
    float*    ob  = (float*)(vbw + nkv);                 // 256*3136 fp32

    qkv_kernel<<<dim3(13, HEADS, 4), 256, 0, stream>>>(x, Wq, bq, Wk, bk, Wv, bv,
                                                        qbw, kbw, vbw);
    attn_kernel<<<dim3(HW / QT, HEADS), 64, 0, stream>>>(qbw, kbw, vbw, rowt, colt, ob);
    outproj_kernel<<<dim3(13, COUTC), 256, 0, stream>>>(ob, Wo, bo, out);
}

// Round 4
// 179.990 us; speedup vs baseline: 4.6040x; 1.1081x over previous
//
#include <hip/hip_runtime.h>
#include <hip/hip_bf16.h>

#define HW    3136
#define CIN   64
#define MIDC  32
#define HEADS 8
#define DTOT  256
#define COUTC 64
#define WDIM  56
#define QT    16          // queries per block
#define NKT   49          // key tiles of 64 (49*64 = 3136 exactly)
#define L2E   1.4426950408889634f

typedef unsigned short ushort_t;
typedef unsigned int   uint_t;
typedef __attribute__((ext_vector_type(8))) short short8;   // 8 bf16 = 4 VGPRs
typedef __attribute__((ext_vector_type(4))) float f32x4;

__device__ __forceinline__ float bf2f(ushort_t u) {
    return __uint_as_float(((uint_t)u) << 16);
}
__device__ __forceinline__ ushort_t f2bf(float f) {          // RNE
    uint_t u = __float_as_uint(f);
    u += 0x7fff + ((u >> 16) & 1);
    return (ushort_t)(u >> 16);
}
__device__ __forceinline__ uint_t pkbf2(float a, float b) {
    return (uint_t)f2bf(a) | ((uint_t)f2bf(b) << 16);
}

// ---------------- Kernel 1: QKV 1x1 conv, fp32 in -> bf16 ws -----------------
// qb,kb: [h][pos][32] row-major; vb: [h][ch][pos] transposed.
// grid (13, 8, 8): 4 mids per block -> 832 blocks (more waves for latency hiding)
__global__ __launch_bounds__(256) void qkv_kernel(
    const float* __restrict__ x,
    const float* __restrict__ Wq, const float* __restrict__ bq,
    const float* __restrict__ Wk, const float* __restrict__ bk,
    const float* __restrict__ Wv, const float* __restrict__ bv,
    ushort_t* __restrict__ qb, ushort_t* __restrict__ kb, ushort_t* __restrict__ vb)
{
    int p  = blockIdx.x * 256 + threadIdx.x;
    int h  = blockIdx.y;
    int m0 = blockIdx.z * 4;
    if (p >= HW) return;
    float qa[4], ka[4], va[4];
    #pragma unroll
    for (int mm = 0; mm < 4; ++mm) {
        int d = (m0 + mm) * HEADS + h;
        qa[mm] = bq[d]; ka[mm] = bk[d]; va[mm] = bv[d];
    }
    #pragma unroll 4
    for (int c = 0; c < CIN; ++c) {
        float xv = x[c * HW + p];      // coalesced across lanes
        #pragma unroll
        for (int mm = 0; mm < 4; ++mm) {
            int d = (m0 + mm) * HEADS + h;   // uniform weight reads (s_load)
            qa[mm] += Wq[d * CIN + c] * xv;
            ka[mm] += Wk[d * CIN + c] * xv;
            va[mm] += Wv[d * CIN + c] * xv;
        }
    }
    uint_t qw[2], kw[2];
    #pragma unroll
    for (int i = 0; i < 2; ++i) {
        qw[i] = pkbf2(qa[2*i], qa[2*i+1]);
        kw[i] = pkbf2(ka[2*i], ka[2*i+1]);
    }
    *(uint2*)&qb[(size_t)h * HW * MIDC + p * MIDC + m0] = *(uint2*)qw;
    *(uint2*)&kb[(size_t)h * HW * MIDC + p * MIDC + m0] = *(uint2*)kw;
    #pragma unroll
    for (int mm = 0; mm < 4; ++mm)
        vb[(size_t)h * HW * MIDC + (m0 + mm) * HW + p] = f2bf(va[mm]);
}

// ---------------- Kernel 2: MFMA flash attention, 4-way K-split --------------
// grid (196, 8), 256 threads = 4 waves sharing one 16-query tile.
__global__ __launch_bounds__(256) void attn_kernel(
    const ushort_t* __restrict__ qb, const ushort_t* __restrict__ kb,
    const ushort_t* __restrict__ vb,
    const float* __restrict__ rowt, const float* __restrict__ colt,
    float* __restrict__ ob)
{
    __shared__ ushort_t Qs[QT][MIDC];                 // 1 KB
    __shared__ float    Rb[QT][57];                   // 3648 B (pad 57)
    __shared__ float    Cb[QT][57];
    __shared__ __align__(16) char pool[9728];         // Pl[4][16][72] ushort (9216B)
                                                      // aliased by merge bufs after loop
    ushort_t* PlBase = (ushort_t*)pool;

    const int tid   = threadIdx.x;
    const int wave  = tid >> 6, lane = tid & 63;
    const int h     = blockIdx.y;
    const int qbase = blockIdx.x * QT;
    const float c1  = 0.125f * L2E;                   // inv * log2(e)

    const ushort_t* Qh = qb + (size_t)h * HW * MIDC;
    const ushort_t* Kh = kb + (size_t)h * HW * MIDC;
    const ushort_t* Vh = vb + (size_t)h * HW * MIDC;  // [ch][pos]

    if (tid < 64) {   // stage Q tile (16q x 32ch bf16 = 1KB)
        int r = tid >> 2, c = (tid & 3) * 8;
        *(uint4*)&Qs[r][c] = *(const uint4*)&Qh[(size_t)(qbase + r) * MIDC + c];
    }
    __syncthreads();

    // bias tables, inv*log2e folded in:
    //  Rb[q][ki] = c1 * sum_{c<16} Q[q][c]    * rowt[ki - qi + 55][c]
    //  Cb[q][kj] = c1 * sum_{c<16} Q[q][16+c] * colt[kj - qj + 55][c]
    for (int idx = tid; idx < QT * WDIM; idx += 256) {
        int qL = idx / WDIM, kp = idx % WDIM;
        int qg = qbase + qL, qi = qg / WDIM, qj = qg % WDIM;
        const float* rt = &rowt[(kp - qi + WDIM - 1) * 16];
        const float* ct = &colt[(kp - qj + WDIM - 1) * 16];
        float s = 0.f, s2 = 0.f;
        #pragma unroll
        for (int c = 0; c < 16; ++c) {
            s  += bf2f(Qs[qL][c])      * rt[c];
            s2 += bf2f(Qs[qL][16 + c]) * ct[c];
        }
        Rb[qL][kp] = s * c1;
        Cb[qL][kp] = s2 * c1;
    }
    __syncthreads();

    const int qL  = lane & 15;
    const int grp = lane >> 4;
    short8 qfrag = *(const short8*)&Qs[qL][grp * 8];

    float m_run = -1e30f, l_run = 0.f;                // log2 domain
    f32x4 o0 = {0.f,0.f,0.f,0.f}, o1 = {0.f,0.f,0.f,0.f};

    // incremental (ki,kj) per s-subtile; lane's key = kb0 + s*16 + grp*4 + r
    int ki_s[4], kj_s[4];
    #pragma unroll
    for (int s = 0; s < 4; ++s) {
        int key = wave * 64 + s * 16 + grp * 4;
        ki_s[s] = key / WDIM;                         // magic-mul, once
        kj_s[s] = key % WDIM;
    }

    ushort_t* Pw = PlBase + wave * (QT * 72);         // per-wave private P tile

    for (int kt = wave; kt < NKT; kt += 4) {
        const int kb0 = kt * 64;
        short8 kf[4];
        #pragma unroll
        for (int s = 0; s < 4; ++s)
            kf[s] = *(const short8*)&Kh[(size_t)(kb0 + s*16 + qL) * MIDC + grp*8];
        short8 vf[2][2];
        #pragma unroll
        for (int ch = 0; ch < 2; ++ch)
            #pragma unroll
            for (int kh = 0; kh < 2; ++kh)
                vf[ch][kh] = *(const short8*)
                    &Vh[(size_t)(ch*16 + qL) * HW + kb0 + kh*32 + grp*8];

        // S^T = K . Q^T
        f32x4 sc[4];
        #pragma unroll
        for (int s = 0; s < 4; ++s) {
            f32x4 z = {0.f,0.f,0.f,0.f};
            sc[s] = __builtin_amdgcn_mfma_f32_16x16x32_bf16(kf[s], qfrag, z, 0,0,0);
        }

        const float* RbL = Rb[qL];
        const float* CbL = Cb[qL];
        float smax = -1e30f;
        #pragma unroll
        for (int s = 0; s < 4; ++s)
            #pragma unroll
            for (int r = 0; r < 4; ++r) {
                int kjr = kj_s[s] + r, kir = ki_s[s];
                if (kjr >= WDIM) { kjr -= WDIM; kir += 1; }
                float v = fmaf(sc[s][r], c1, RbL[kir] + CbL[kjr]);
                sc[s][r] = v;
                smax = fmaxf(smax, v);
            }
        smax = fmaxf(smax, __shfl_xor(smax, 16));
        smax = fmaxf(smax, __shfl_xor(smax, 32));
        float m_new = fmaxf(m_run, smax);
        float alpha = __builtin_amdgcn_exp2f(m_run - m_new);
        float lsum = 0.f;
        uint_t pw[8];
        #pragma unroll
        for (int s = 0; s < 4; ++s) {
            float p0 = __builtin_amdgcn_exp2f(sc[s][0] - m_new);
            float p1 = __builtin_amdgcn_exp2f(sc[s][1] - m_new);
            float p2 = __builtin_amdgcn_exp2f(sc[s][2] - m_new);
            float p3 = __builtin_amdgcn_exp2f(sc[s][3] - m_new);
            lsum += (p0 + p1) + (p2 + p3);
            pw[s*2+0] = pkbf2(p0, p1);
            pw[s*2+1] = pkbf2(p2, p3);
        }
        lsum += __shfl_xor(lsum, 16);
        lsum += __shfl_xor(lsum, 32);
        l_run = l_run * alpha + lsum;
        m_run = m_new;
        #pragma unroll
        for (int i = 0; i < 4; ++i) { o0[i] *= alpha; o1[i] *= alpha; }

        #pragma unroll
        for (int s = 0; s < 4; ++s) {
            uint2 w2; w2.x = pw[s*2]; w2.y = pw[s*2+1];
            *(uint2*)&Pw[qL*72 + s*16 + grp*4] = w2;
        }

        // O^T += V^T . P^T
        #pragma unroll
        for (int kh = 0; kh < 2; ++kh) {
            short8 pf = *(const short8*)&Pw[qL*72 + kh*32 + grp*8];
            o0 = __builtin_amdgcn_mfma_f32_16x16x32_bf16(vf[0][kh], pf, o0, 0,0,0);
            o1 = __builtin_amdgcn_mfma_f32_16x16x32_bf16(vf[1][kh], pf, o1, 0,0,0);
        }

        #pragma unroll
        for (int s = 0; s < 4; ++s) {                 // advance keys by 256
            kj_s[s] += 32;
            if (kj_s[s] >= WDIM) { kj_s[s] -= WDIM; ki_s[s] += 5; }
            else                 { ki_s[s] += 4; }
        }
    }

    // ---- merge the 4 waves' online-softmax states (alias pool) ----
    __syncthreads();                                  // all waves done with Pl
    float* MOb = (float*)pool;                        // [4][16][36] (pad 36, 16B-aligned rows)
    float* Ml  = MOb + 4 * 16 * 36;                   // [4][16]
    float* Ll  = Ml + 64;

    *(f32x4*)&MOb[(wave*16 + qL)*36 + grp*4]      = o0;   // ch 0..15
    *(f32x4*)&MOb[(wave*16 + qL)*36 + 16 + grp*4] = o1;   // ch 16..31
    if (grp == 0) { Ml[wave*16 + qL] = m_run; Ll[wave*16 + qL] = l_run; }
    __syncthreads();

    {
        int q = tid & 15, ch0 = (tid >> 4) * 2;       // q fastest -> coalesced ob writes
        float mM = fmaxf(fmaxf(Ml[q], Ml[16+q]), fmaxf(Ml[32+q], Ml[48+q]));
        float acc0 = 0.f, acc1 = 0.f, lt = 0.f;
        #pragma unroll
        for (int w = 0; w < 4; ++w) {
            float e = __builtin_amdgcn_exp2f(Ml[w*16+q] - mM);
            lt   += Ll[w*16+q] * e;
            acc0 += MOb[(w*16+q)*36 + ch0]     * e;
            acc1 += MOb[(w*16+q)*36 + ch0 + 1] * e;
        }
        float invl = 1.f / lt;
        int qg = qbase + q;
        ob[(size_t)(h*MIDC + ch0)     * HW + qg] = acc0 * invl;
        ob[(size_t)(h*MIDC + ch0 + 1) * HW + qg] = acc1 * invl;
    }
}

// ---------------- Kernel 3: output 1x1 conv (fp32 ws -> fp32 out) ------------
// ob channel layout: c_total = m*8+h lives at row (h*32+m)
__global__ __launch_bounds__(256) void outproj_kernel(
    const float* __restrict__ ob, const float* __restrict__ Wo,
    const float* __restrict__ bo, float* __restrict__ out)
{
    int p = blockIdx.x * 256 + threadIdx.x;
    int d = blockIdx.y;
    if (p >= HW) return;
    float s = bo[d];
    #pragma unroll 8
    for (int c = 0; c < DTOT; ++c) {
        int m = c >> 3, h = c & 7;
        s += Wo[d * DTOT + c] * ob[(size_t)(h * MIDC + m) * HW + p];
    }
    out[d * HW + p] = s;
}

extern "C" void kernel_launch(void* const* d_in, const int* in_sizes, int n_in,
                              void* d_out, int out_size, void* d_ws, size_t ws_size,
                              hipStream_t stream)
{
    const float* x    = (const float*)d_in[0];
    const float* Wq   = (const float*)d_in[1];
    const float* bq   = (const float*)d_in[2];
    const float* Wk   = (const float*)d_in[3];
    const float* bk   = (const float*)d_in[4];
    const float* Wv   = (const float*)d_in[5];
    const float* bv   = (const float*)d_in[6];
    const float* Wo   = (const float*)d_in[7];
    const float* bo   = (const float*)d_in[8];
    const float* rowt = (const float*)d_in[9];
    const float* colt = (const float*)d_in[10];
    float* out = (float*)d_out;

    const size_t nkv = (size_t)HEADS * HW * MIDC;       // 802816 elems
    ushort_t* qbw = (ushort_t*)d_ws;
    ushort_t* kbw = qbw + nkv;
    ushort_t* vbw = kbw + nkv;
    float*    ob  = (float*)(vbw + nkv);                 // 256*3136 fp32

    qkv_kernel<<<dim3(13, HEADS, 8), 256, 0, stream>>>(x, Wq, bq, Wk, bk, Wv, bv,
                                                        qbw, kbw, vbw);
    attn_kernel<<<dim3(HW / QT, HEADS), 256, 0, stream>>>(qbw, kbw, vbw, rowt, colt, ob);
    outproj_kernel<<<dim3(13, COUTC), 256, 0, stream>>>(ob, Wo, bo, out);
}